// Round 2
// baseline (228.970 us; speedup 1.0000x reference)
//
#include <hip/hip_runtime.h>

// fastmax attention. b=4,h=16,n=1024,d=64 fp32. bf16x3 split precision.
// Prep kernels unchanged: split k (l2-normalized), v'=v+0.1*noise (transposed),
// rpe into bf16 hi/lo arrays in d_ws.
// Main kernel v2: 32-row q-tiles, 64-col k-tiles, 4 waves own 16q x 32j
// quadrants. RPE is NOT staged (512 KB, L2-resident -> direct coalesced
// global reads for QR B-frags). LDS = 36,864 B (K/V hi/lo only) -> 4
// blocks/CU, 16 waves/CU (2x occupancy vs v1). Grid 1024 = 16 pairs x 64 bh;
// pair (t, 31-t) gives every block exactly 17 K-iters. Per-wave scratch
// (Bst 48x18 f32, then S hi/lo) overlays dead Kh/Kl between barriers B..D.
// Cross-wave (jh) O/denom reduction via LDS at tile end.

constexpr int N   = 1024;
constexpr int D   = 64;
constexpr int NBH = 64;
constexpr int LDT = 72;   // ushort stride of staged tiles

// ws layout (bytes) — unchanged
constexpr size_t KH_OFF = 0;                                  // k_hi [bh][row][t]
constexpr size_t KL_OFF = KH_OFF + (size_t)NBH * N * D * 2;
constexpr size_t VH_OFF = KL_OFF + (size_t)NBH * N * D * 2;   // vt_hi [bh][dc][c]
constexpr size_t VL_OFF = VH_OFF + (size_t)NBH * N * D * 2;
constexpr size_t RH_OFF = VL_OFF + (size_t)NBH * N * D * 2;   // r_hi [rel 2048][t]
constexpr size_t RL_OFF = RH_OFF + (size_t)2048 * D * 2;

typedef short short8  __attribute__((ext_vector_type(8)));
typedef float float4v __attribute__((ext_vector_type(4)));

#define LDS_FENCE() asm volatile("s_waitcnt lgkmcnt(0)" ::: "memory")

__device__ __forceinline__ ushort f2bf(float x) {
    union { float f; unsigned u; } un; un.f = x;
    unsigned r = un.u + 0x7fffu + ((un.u >> 16) & 1u);   // RNE
    return (ushort)(r >> 16);
}
__device__ __forceinline__ float bf2f(ushort h) {
    union { unsigned u; float f; } un; un.u = ((unsigned)h) << 16;
    return un.f;
}
__device__ __forceinline__ void split2(float x, ushort& h, ushort& l) {
    h = f2bf(x);
    l = f2bf(x - bf2f(h));
}
__device__ __forceinline__ void pack16(const float* v, ushort* dh, ushort* dl) {
    ushort hh[16], ll[16];
#pragma unroll
    for (int j = 0; j < 16; ++j) split2(v[j], hh[j], ll[j]);
    uint4 a, b;
    a.x = hh[0] | (hh[1] << 16);  a.y = hh[2] | (hh[3] << 16);
    a.z = hh[4] | (hh[5] << 16);  a.w = hh[6] | (hh[7] << 16);
    b.x = hh[8] | (hh[9] << 16);  b.y = hh[10] | (hh[11] << 16);
    b.z = hh[12] | (hh[13] << 16); b.w = hh[14] | (hh[15] << 16);
    ((uint4*)dh)[0] = a; ((uint4*)dh)[1] = b;
    a.x = ll[0] | (ll[1] << 16);  a.y = ll[2] | (ll[3] << 16);
    a.z = ll[4] | (ll[5] << 16);  a.w = ll[6] | (ll[7] << 16);
    b.x = ll[8] | (ll[9] << 16);  b.y = ll[10] | (ll[11] << 16);
    b.z = ll[12] | (ll[13] << 16); b.w = ll[14] | (ll[15] << 16);
    ((uint4*)dl)[0] = a; ((uint4*)dl)[1] = b;
}

// ---- pre-kernels (unchanged) ----
__global__ __launch_bounds__(256) void prep_k(const float* __restrict__ kg,
                                              ushort* __restrict__ kh,
                                              ushort* __restrict__ kl) {
    const int bh = blockIdx.y;
    const int row = blockIdx.x * 64 + (threadIdx.x >> 2);
    const int seg = threadIdx.x & 3;
    const float4* p = (const float4*)(kg + ((size_t)bh * N + row) * D + seg * 16);
    float4 f[4] = {p[0], p[1], p[2], p[3]};
    float ss = 0.f;
#pragma unroll
    for (int i = 0; i < 4; ++i)
        ss += f[i].x * f[i].x + f[i].y * f[i].y + f[i].z * f[i].z + f[i].w * f[i].w;
    ss += __shfl_xor(ss, 1, 4);
    ss += __shfl_xor(ss, 2, 4);
    const float rn = rsqrtf(ss);
    float v[16];
#pragma unroll
    for (int i = 0; i < 4; ++i) {
        v[4 * i + 0] = f[i].x * rn; v[4 * i + 1] = f[i].y * rn;
        v[4 * i + 2] = f[i].z * rn; v[4 * i + 3] = f[i].w * rn;
    }
    const size_t o = ((size_t)bh * N + row) * D + seg * 16;
    pack16(v, kh + o, kl + o);
}

__global__ __launch_bounds__(256) void prep_rpe(const float* __restrict__ rg,
                                                ushort* __restrict__ rh,
                                                ushort* __restrict__ rl) {
    const int row = blockIdx.x * 64 + (threadIdx.x >> 2);
    if (row >= 2 * N - 1) return;
    const int seg = threadIdx.x & 3;
    const float4* p = (const float4*)(rg + (size_t)row * D + seg * 16);
    float4 f[4] = {p[0], p[1], p[2], p[3]};
    float v[16];
#pragma unroll
    for (int i = 0; i < 4; ++i) {
        v[4 * i + 0] = f[i].x; v[4 * i + 1] = f[i].y;
        v[4 * i + 2] = f[i].z; v[4 * i + 3] = f[i].w;
    }
    const size_t o = (size_t)row * D + seg * 16;
    pack16(v, rh + o, rl + o);
}

__global__ __launch_bounds__(256) void prep_v(const float* __restrict__ vg,
                                              const float* __restrict__ ng,
                                              ushort* __restrict__ vh,
                                              ushort* __restrict__ vl) {
    __shared__ ushort Th[64 * 72], Tl[64 * 72];
    const int bh = blockIdx.y, c0 = blockIdx.x * 64;
    const int cl = threadIdx.x >> 2, seg = threadIdx.x & 3;
    {
        const float4* pv = (const float4*)(vg + ((size_t)bh * N + c0 + cl) * D + seg * 16);
        const float4* pn = (const float4*)(ng + ((size_t)bh * N + c0 + cl) * D + seg * 16);
#pragma unroll
        for (int i = 0; i < 4; ++i) {
            float4 fv = pv[i], fn = pn[i];
            float va[4] = {fv.x + 0.1f * fn.x, fv.y + 0.1f * fn.y,
                           fv.z + 0.1f * fn.z, fv.w + 0.1f * fn.w};
#pragma unroll
            for (int j = 0; j < 4; ++j) {
                ushort hh, ll;
                split2(va[j], hh, ll);
                const int dc = seg * 16 + i * 4 + j;
                Th[dc * 72 + cl] = hh;
                Tl[dc * 72 + cl] = ll;
            }
        }
    }
    __syncthreads();
    {
        const int dc = threadIdx.x >> 2;
        const size_t o = ((size_t)bh * D + dc) * N + c0 + seg * 16;
        uint4* sh = (uint4*)&Th[dc * 72 + seg * 16];
        uint4* sl = (uint4*)&Tl[dc * 72 + seg * 16];
        ((uint4*)(vh + o))[0] = sh[0]; ((uint4*)(vh + o))[1] = sh[1];
        ((uint4*)(vl + o))[0] = sl[0]; ((uint4*)(vl + o))[1] = sl[1];
    }
}

// ---- main ----
__device__ __forceinline__ float4v mfma6(short8 ah0, short8 ah1, short8 al0, short8 al1,
                                         const ushort* ph, const ushort* pl, float4v c) {
    short8 bh0 = *(const short8*)ph;
    short8 bh1 = *(const short8*)(ph + 32);
    short8 bl0 = *(const short8*)pl;
    short8 bl1 = *(const short8*)(pl + 32);
    c = __builtin_amdgcn_mfma_f32_16x16x32_bf16(ah0, bh0, c, 0, 0, 0);
    c = __builtin_amdgcn_mfma_f32_16x16x32_bf16(ah1, bh1, c, 0, 0, 0);
    c = __builtin_amdgcn_mfma_f32_16x16x32_bf16(ah0, bl0, c, 0, 0, 0);
    c = __builtin_amdgcn_mfma_f32_16x16x32_bf16(ah1, bl1, c, 0, 0, 0);
    c = __builtin_amdgcn_mfma_f32_16x16x32_bf16(al0, bh0, c, 0, 0, 0);
    c = __builtin_amdgcn_mfma_f32_16x16x32_bf16(al1, bh1, c, 0, 0, 0);
    return c;
}

// K=32 variant for PV (S is 16x32 per wave)
__device__ __forceinline__ float4v mfma3(short8 ah, short8 al,
                                         const ushort* ph, const ushort* pl, float4v c) {
    short8 bh0 = *(const short8*)ph;
    short8 bl0 = *(const short8*)pl;
    c = __builtin_amdgcn_mfma_f32_16x16x32_bf16(ah, bh0, c, 0, 0, 0);
    c = __builtin_amdgcn_mfma_f32_16x16x32_bf16(ah, bl0, c, 0, 0, 0);
    c = __builtin_amdgcn_mfma_f32_16x16x32_bf16(al, bh0, c, 0, 0, 0);
    return c;
}

__global__ __launch_bounds__(256, 4)
void fastmax_main(const float* __restrict__ qg,
                  const ushort* __restrict__ kh, const ushort* __restrict__ kl,
                  const ushort* __restrict__ vh, const ushort* __restrict__ vl,
                  const ushort* __restrict__ rh, const ushort* __restrict__ rl,
                  float* __restrict__ og) {
    // LDS 36,864 B -> 4 blocks/CU. Scratch + reduction buffers overlay Kh/Kl
    // (dead between barrier B and next staging).
    __shared__ __align__(16) char smem[36864];
    ushort* Kh = (ushort*)smem;           // [64][LDT]
    ushort* Kl = Kh + 64 * LDT;
    ushort* Vh = Kl + 64 * LDT;           // [64][LDT] (dc-major)
    ushort* Vl = Vh + 64 * LDT;

    const int tid  = threadIdx.x;
    const int lane = tid & 63;
    const int wv   = tid >> 6;
    const int bh   = blockIdx.y;
    const int x    = lane & 15;
    const int quad = lane >> 4;
    const int qh   = wv >> 1;   // which 16-row half of the 32-row q-tile
    const int jh   = wv & 1;    // which 32-col half of the 64-col k-tile

    const ushort* khb = kh + (size_t)bh * N * D;
    const ushort* klb = kl + (size_t)bh * N * D;
    const ushort* vhb = vh + (size_t)bh * D * N;
    const ushort* vlb = vl + (size_t)bh * D * N;

    for (int half = 0; half < 2; ++half) {
        // pair (tq, 31-tq): iteration counts sum to exactly 17 for every block
        const int tq  = half == 0 ? (int)blockIdx.x + 16 : 15 - (int)blockIdx.x;
        const int i0  = tq * 32;
        const int nJt = (tq >> 1) + 1;

        // ---- this wave's 16 q rows -> normalized bf16x2 A-frags ----
        const float* qrow = qg + ((size_t)bh * N + i0 + qh * 16 + x) * D;
        float qf[16];
        *(float4*)&qf[0]  = *(const float4*)(qrow + quad * 8);
        *(float4*)&qf[4]  = *(const float4*)(qrow + quad * 8 + 4);
        *(float4*)&qf[8]  = *(const float4*)(qrow + 32 + quad * 8);
        *(float4*)&qf[12] = *(const float4*)(qrow + 32 + quad * 8 + 4);
        float ss = 0.f;
#pragma unroll
        for (int j = 0; j < 16; ++j) ss += qf[j] * qf[j];
        ss += __shfl_xor(ss, 16);
        ss += __shfl_xor(ss, 32);
        const float rn = rsqrtf(ss);
        short8 qh0, ql0, qh1, ql1;
#pragma unroll
        for (int j = 0; j < 8; ++j) {
            ushort h, l;
            split2(qf[j] * rn, h, l);      qh0[j] = (short)h; ql0[j] = (short)l;
            split2(qf[8 + j] * rn, h, l);  qh1[j] = (short)h; ql1[j] = (short)l;
        }

        float4v oacc[4];
#pragma unroll
        for (int i = 0; i < 4; ++i) oacc[i] = (float4v){0.f, 0.f, 0.f, 0.f};
        float pden[4] = {0.f, 0.f, 0.f, 0.f};

        for (int jt = 0; jt < nJt; ++jt) {
            const int j0 = jt * 64;

            // ---- stage K,V tiles: pure b128 copies (pre-split data) ----
            {
                const ushort* gKh = khb + (size_t)j0 * D;
                const ushort* gKl = klb + (size_t)j0 * D;
                const ushort* gVh = vhb + j0;   // rows dc, stride N
                const ushort* gVl = vlb + j0;
                for (int u = tid; u < 512; u += 256) {
                    const int row = u >> 3, c8 = (u & 7) * 8;
                    *(uint4*)&Kh[row * LDT + c8] = *(const uint4*)&gKh[row * D + c8];
                    *(uint4*)&Kl[row * LDT + c8] = *(const uint4*)&gKl[row * D + c8];
                    *(uint4*)&Vh[row * LDT + c8] = *(const uint4*)&gVh[(size_t)row * N + c8];
                    *(uint4*)&Vl[row * LDT + c8] = *(const uint4*)&gVl[(size_t)row * N + c8];
                }
            }
            __syncthreads();   // A: staging done

            // ---- QK^T: wave's 16 rows x 32 cols ----
            float4v sacc[2];
#pragma unroll
            for (int nt = 0; nt < 2; ++nt) {
                const int off = (jh * 32 + nt * 16 + x) * LDT + quad * 8;
                float4v c = (float4v){0.f, 0.f, 0.f, 0.f};
                sacc[nt] = mfma6(qh0, qh1, ql0, ql1, &Kh[off], &Kl[off], c);
            }

            // ---- QR: B-frags straight from global (RPE split = 512 KB, L2-hit).
            // Wave's bias window is 47 wide -> 3 aligned 16-tiles starting at w0.
            // Max touched row is 2047 (allocated; value never gathered).
            const int w0 = (i0 - j0 + N - 64) + 32 + qh * 16 - jh * 32;
            float4v racc[3];
#pragma unroll
            for (int t = 0; t < 3; ++t) {
                const size_t ro = (size_t)(w0 + t * 16 + x) * D + quad * 8;
                float4v c = (float4v){0.f, 0.f, 0.f, 0.f};
                racc[t] = mfma6(qh0, qh1, ql0, ql1, rh + ro, rl + ro, c);
            }
            __syncthreads();   // B: all Kh/Kl reads done; scratch region free

            // ---- intra-wave Bst transpose (scratch overlays Kh/Kl) ----
            float* Bst = (float*)(smem + wv * 3456);   // [48][18] f32
#pragma unroll
            for (int t = 0; t < 3; ++t) {
                float* p = &Bst[(t * 16 + x) * 18 + quad * 4];
                float2 a; a.x = racc[t][0]; a.y = racc[t][1];
                float2 b; b.x = racc[t][2]; b.y = racc[t][3];
                *(float2*)p = a;
                *(float2*)(p + 2) = b;
            }
            LDS_FENCE();

            // ---- gather bias, assemble S, denom ----
            const bool diag = (jt == nJt - 1);
            float s[2][4];
#pragma unroll
            for (int nt = 0; nt < 2; ++nt) {
#pragma unroll
                for (int rr = 0; rr < 4; ++rr) {
                    const int wl = 31 + quad * 4 + rr - nt * 16 - x;   // [0,46]
                    float val = sacc[nt][rr] + Bst[wl * 18 + quad * 4 + rr] + 1.0f;
                    if (diag) {
                        const int ia = i0 + qh * 16 + quad * 4 + rr;
                        const int ja = j0 + jh * 32 + nt * 16 + x;
                        if (ja > ia) val = 0.f;
                    }
                    pden[rr] += val;
                    s[nt][rr] = val;
                }
            }
            LDS_FENCE();

            // ---- intra-wave S hi/lo store + A-frag reload (K=32) ----
            ushort* Sh = (ushort*)(smem + wv * 3456);  // [16][36]
            ushort* Sl = Sh + 16 * 36;
#pragma unroll
            for (int nt = 0; nt < 2; ++nt)
#pragma unroll
                for (int rr = 0; rr < 4; ++rr) {
                    ushort hh2, ll2;
                    split2(s[nt][rr], hh2, ll2);
                    Sh[(quad * 4 + rr) * 36 + nt * 16 + x] = hh2;
                    Sl[(quad * 4 + rr) * 36 + nt * 16 + x] = ll2;
                }
            LDS_FENCE();
            const short8 sh0 = *(const short8*)&Sh[x * 36 + quad * 8];
            const short8 sl0 = *(const short8*)&Sl[x * 36 + quad * 8];

            // ---- O += S @ V' over wave's 32 j-rows ----
#pragma unroll
            for (int nt = 0; nt < 4; ++nt) {
                const int off = (nt * 16 + x) * LDT + jh * 32 + quad * 8;
                oacc[nt] = mfma3(sh0, sl0, &Vh[off], &Vl[off], oacc[nt]);
            }
            __syncthreads();   // D: all reads done; next iter may restage
        }

        // ---- cross-wave (jh) reduction of O partials + denom, store ----
        float den[4];
#pragma unroll
        for (int rr = 0; rr < 4; ++rr) {
            float d = pden[rr];
            d += __shfl_xor(d, 1, 16);
            d += __shfl_xor(d, 2, 16);
            d += __shfl_xor(d, 4, 16);
            d += __shfl_xor(d, 8, 16);
            den[rr] = d;
        }
        float* Obuf = (float*)smem + (size_t)qh * 1088;   // [16][68] per qh
        float* Dbuf = (float*)smem + 2176;                // [2][16]
        if (jh == 1) {
#pragma unroll
            for (int nt = 0; nt < 4; ++nt)
#pragma unroll
                for (int rr = 0; rr < 4; ++rr)
                    Obuf[(quad * 4 + rr) * 68 + nt * 16 + x] = oacc[nt][rr];
            if (x == 0) {
#pragma unroll
                for (int rr = 0; rr < 4; ++rr)
                    Dbuf[qh * 16 + quad * 4 + rr] = den[rr];
            }
        }
        __syncthreads();   // E: partials visible
        if (jh == 0) {
            float inv[4];
#pragma unroll
            for (int rr = 0; rr < 4; ++rr)
                inv[rr] = 1.0f / (den[rr] + Dbuf[qh * 16 + quad * 4 + rr]);
            float* outp = og + ((size_t)bh * N + i0 + qh * 16) * D;
#pragma unroll
            for (int nt = 0; nt < 4; ++nt)
#pragma unroll
                for (int rr = 0; rr < 4; ++rr)
                    outp[(size_t)(quad * 4 + rr) * D + nt * 16 + x] =
                        (oacc[nt][rr] + Obuf[(quad * 4 + rr) * 68 + nt * 16 + x]) * inv[rr];
        }
        __syncthreads();   // F: Obuf/Dbuf consumed before next tile staging
    }
}

extern "C" void kernel_launch(void* const* d_in, const int* in_sizes, int n_in,
                              void* d_out, int out_size, void* d_ws, size_t ws_size,
                              hipStream_t stream) {
    const float* q   = (const float*)d_in[0];
    const float* k   = (const float*)d_in[1];
    const float* v   = (const float*)d_in[2];
    const float* dn  = (const float*)d_in[3];
    const float* rpe = (const float*)d_in[4];
    float* out = (float*)d_out;
    char* ws = (char*)d_ws;

    ushort* kh = (ushort*)(ws + KH_OFF);
    ushort* kl = (ushort*)(ws + KL_OFF);
    ushort* vh = (ushort*)(ws + VH_OFF);
    ushort* vl = (ushort*)(ws + VL_OFF);
    ushort* rh = (ushort*)(ws + RH_OFF);
    ushort* rl = (ushort*)(ws + RL_OFF);

    prep_k  <<<dim3(N / 64, NBH), 256, 0, stream>>>(k, kh, kl);
    prep_v  <<<dim3(N / 64, NBH), 256, 0, stream>>>(v, dn, vh, vl);
    prep_rpe<<<dim3(32), 256, 0, stream>>>(rpe, rh, rl);
    fastmax_main<<<dim3(16, NBH), 256, 0, stream>>>(q, kh, kl, vh, vl, rh, rl, out);
}